// Round 11
// baseline (217.527 us; speedup 1.0000x reference)
//
#include <hip/hip_runtime.h>

// ValleFlashAttention on MI355X (gfx950).
// B=2, N=2048, C=1024, H=16, hd=64. PAD_TAIL=128 (keys >= 1920 masked).
// causal_start read from d_in[2].
//
// Round 15 (= Round 14 resubmitted byte-identical; R14 bench was an infra
// failure "container failed twice" with no diagnostics, same as Round 0):
//  - GEMMs: triple-buffered staging with COUNTED vmcnt (T4). Per step:
//    stage(t+2) -> compute(t) -> s_waitcnt vmcnt(L) -> raw s_barrier.
//    The counted wait (L = loads/stage) completes tile t+1 for ALL waves
//    before the barrier releases readers; tile t+2's loads stay in flight
//    ACROSS the barrier. R9 showed doubling TLP didn't help gemm0 ->
//    the correlated vmcnt(0) drain at __syncthreads was the stall.
//    gemm0: 128x128, grid 768 (3/CU, LDS 48K). gemm1: 128x64, grid 512.
//  - attn: exp2f -> raw v_exp_f32 (top counter was VALUBusy 59%; OCML exp2
//    is a guarded multi-instr sequence). Everything else byte-identical to
//    R12's 49.9 us kernel.

typedef unsigned short ushort_t;
typedef short short8 __attribute__((ext_vector_type(8)));
typedef float floatx4 __attribute__((ext_vector_type(4)));
typedef unsigned short ushort4v __attribute__((ext_vector_type(4)));

#define MFMA16(a, b, c) __builtin_amdgcn_mfma_f32_16x16x32_bf16(a, b, c, 0, 0, 0)

__device__ __forceinline__ ushort_t f2bf(float f) {   // RNE
  unsigned int u = __float_as_uint(f);
  u += 0x7fffu + ((u >> 16) & 1u);
  return (ushort_t)(u >> 16);
}

__device__ __forceinline__ float fexp2(float x) {  // raw v_exp_f32 (exp2)
  float r;
  asm("v_exp_f32 %0, %1" : "=v"(r) : "v"(x));
  return r;
}

// async global->LDS, 16B per lane; LDS dest must be wave-uniform base + lane*16.
__device__ __forceinline__ void gl_lds16(const ushort_t* g, ushort_t* l) {
  __builtin_amdgcn_global_load_lds(
      (const __attribute__((address_space(1))) void*)g,
      (__attribute__((address_space(3))) void*)l, 16, 0, 0);
}

// ---------------------------------------------------------------- cvt fp32->bf16
__global__ __launch_bounds__(256) void cvt_all_kernel(
    const float* __restrict__ x, const float* __restrict__ wq,
    const float* __restrict__ wp, ushort_t* __restrict__ xb,
    ushort_t* __restrict__ wqb, ushort_t* __restrict__ wpb) {
  int i = (blockIdx.x * 256 + threadIdx.x) * 4;
  const float* s;
  ushort_t* d;
  int off;
  if (i < (4 << 20)) {            // x: 4096*1024
    s = x; d = xb; off = i;
  } else if (i < (7 << 20)) {     // w_qkv: 3072*1024
    s = wq; d = wqb; off = i - (4 << 20);
  } else {                        // w_proj: 1024*1024
    s = wp; d = wpb; off = i - (7 << 20);
  }
  float4 v = *(const float4*)(s + off);
  ushort4v o;
  o.x = f2bf(v.x); o.y = f2bf(v.y); o.z = f2bf(v.z); o.w = f2bf(v.w);
  *(ushort4v*)(d + off) = o;
}

// ---------------------------------------------------------------- GEMM (B^T form)
// C[m][n] = sum_k A[m][k] * Bm[n][k].  128xNT tile, BK=32, 4 waves.
// Triple-buffered LDS, counted-vmcnt protocol (see header). 2D XCD rectangles:
// xcd=bid&7 owns 8 tm x TNC tn tiles (tm-inner). Grid = 8 * 8 * TNC.
template <int EPI, int NT>
__global__ __launch_bounds__(256) void gemm_bt(
    const ushort_t* __restrict__ A, const ushort_t* __restrict__ Bm,
    int K, int TNC,
    float* __restrict__ outf, float* __restrict__ present,
    ushort_t* __restrict__ q_ws, ushort_t* __restrict__ k_ws,
    ushort_t* __restrict__ vT_ws, const float* __restrict__ b_proj) {
  constexpr int ABUF = 128 * 32;          // ushorts per A buffer
  constexpr int BBUF = NT * 32;           // ushorts per B buffer
  constexpr int BNF = NT / 32;            // B fragments per wave
  __shared__ __align__(16) ushort_t As[3 * ABUF];
  __shared__ __align__(16) ushort_t Bs[3 * BBUF];
  const int tid = threadIdx.x;
  const int wave = tid >> 6, lane = tid & 63;
  const int quad = lane >> 4, l16 = lane & 15;
  const int wm = wave >> 1, wn = wave & 1;
  // 2D XCD rectangle mapping (tm-inner)
  const int xcd = blockIdx.x & 7;
  const int loc = blockIdx.x >> 3;
  const int tm = (xcd >> 1) * 8 + (loc & 7);
  const int tn = (xcd & 1) * TNC + (loc >> 3);

  const int r0 = tid >> 2, c0 = (tid & 3) * 8;
  const int r1 = r0 + 64;
  const ushort_t* a0 = A + (size_t)(tm * 128 + r0) * K + c0;
  const ushort_t* a1 = A + (size_t)(tm * 128 + r1) * K + c0;
  const ushort_t* b0 = Bm + (size_t)(tn * NT + r0) * K + c0;
  const ushort_t* b1 = (NT == 128) ? Bm + (size_t)(tn * NT + r1) * K + c0 : Bm;
  ushort_t* lA0 = As + tid * 8;
  ushort_t* lA1 = As + (tid + 256) * 8;
  ushort_t* lB0 = Bs + tid * 8;
  ushort_t* lB1 = Bs + (tid + 256) * 8;

  auto stage = [&](int bsel, int k0) {
    gl_lds16(a0 + k0, lA0 + bsel * ABUF);
    gl_lds16(a1 + k0, lA1 + bsel * ABUF);
    gl_lds16(b0 + k0, lB0 + bsel * BBUF);
    if constexpr (NT == 128) gl_lds16(b1 + k0, lB1 + bsel * BBUF);
  };

  floatx4 acc[4][BNF] = {};

  // prologue: 2-deep prefetch; wait tile 0 (counted), tile 1 stays in flight.
  stage(0, 0);
  stage(1, 32);
  if constexpr (NT == 128) asm volatile("s_waitcnt vmcnt(4)" ::: "memory");
  else                     asm volatile("s_waitcnt vmcnt(3)" ::: "memory");
  asm volatile("" ::: "memory");
  __builtin_amdgcn_s_barrier();
  asm volatile("" ::: "memory");

  int cur = 0, stg = 2;
  for (int k0 = 0; k0 < K; k0 += 32) {
    if (k0 + 64 < K) stage(stg, k0 + 64);
    const ushort_t* as = As + cur * ABUF;
    const ushort_t* bs = Bs + cur * BBUF;
    short8 af[4], bfr[BNF];
#pragma unroll
    for (int mi = 0; mi < 4; ++mi)
      af[mi] = *(const short8*)(as + (wm * 64 + mi * 16 + l16) * 32 + quad * 8);
#pragma unroll
    for (int ni = 0; ni < BNF; ++ni)
      bfr[ni] = *(const short8*)(bs + (wn * (NT / 2) + ni * 16 + l16) * 32 + quad * 8);
#pragma unroll
    for (int mi = 0; mi < 4; ++mi)
#pragma unroll
      for (int ni = 0; ni < BNF; ++ni)
        acc[mi][ni] = MFMA16(af[mi], bfr[ni], acc[mi][ni]);

    if (k0 + 32 < K) {
      if (k0 + 64 < K) {  // steady state: wait oldest stage (tile cur+1) only
        if constexpr (NT == 128) asm volatile("s_waitcnt vmcnt(4)" ::: "memory");
        else                     asm volatile("s_waitcnt vmcnt(3)" ::: "memory");
      } else {            // tail: drain the last stage
        asm volatile("s_waitcnt vmcnt(0)" ::: "memory");
      }
      asm volatile("" ::: "memory");
      __builtin_amdgcn_s_barrier();
      asm volatile("" ::: "memory");
    }
    cur = (cur == 2) ? 0 : cur + 1;
    stg = (stg == 2) ? 0 : stg + 1;
  }

#pragma unroll
  for (int mi = 0; mi < 4; ++mi) {
#pragma unroll
    for (int ni = 0; ni < BNF; ++ni) {
      const int gm0 = tm * 128 + wm * 64 + mi * 16 + quad * 4;
      const int gn = tn * NT + wn * (NT / 2) + ni * 16 + l16;
      if constexpr (EPI == 0) {
        const int b = gm0 >> 11, pos0 = gm0 & 2047;
        const int which = gn >> 10, rem = gn & 1023;
        const int h = rem >> 6, d = rem & 63;
        const size_t hb = (size_t)(b * 16 + h);
        if (which == 0) {
          // Q pre-scaled by hd^-0.5 * log2(e) so softmax runs in exp2 domain.
#pragma unroll
          for (int r = 0; r < 4; ++r)
            q_ws[(hb * 2048 + pos0 + r) * 64 + d] =
                f2bf(acc[mi][ni][r] * 0.1803368867f);
        } else if (which == 1) {
#pragma unroll
          for (int r = 0; r < 4; ++r) {
            size_t pk = (hb * 2048 + pos0 + r) * 64 + d;
            present[pk] = acc[mi][ni][r];
            k_ws[pk] = f2bf(acc[mi][ni][r]);
          }
        } else {
#pragma unroll
          for (int r = 0; r < 4; ++r)
            present[((size_t)((2 + b) * 16 + h) * 2048 + pos0 + r) * 64 + d] =
                acc[mi][ni][r];
          ushort4v pk4;
          pk4.x = f2bf(acc[mi][ni][0]); pk4.y = f2bf(acc[mi][ni][1]);
          pk4.z = f2bf(acc[mi][ni][2]); pk4.w = f2bf(acc[mi][ni][3]);
          *(ushort4v*)(vT_ws + (hb * 64 + d) * 2048 + pos0) = pk4;
        }
      } else {
#pragma unroll
        for (int r = 0; r < 4; ++r)
          outf[(size_t)(gm0 + r) * 1024 + gn] = acc[mi][ni][r] + b_proj[gn];
      }
    }
  }
}

// ---------------------------------------------------------------- flash attention
// grid = 1024: bid -> bh = bid&31; j = bid>>5, i = j&7, g = j>>3,
// qt = {i, 31-i, 8+i, 23-i}[g]  (per-CU tile-load == 66 for every CU under
// round-robin dispatch with all 4 blocks/CU resident).
// One 64-row q-tile per block, 4 waves x 16 q-rows. BK=64, K/V double-buffered,
// 1 barrier/tile. LDS 32 KB -> 4 blocks/CU. Permuted K rows make each lane's
// scores exactly the PV B-fragment (no P LDS round-trip).
__global__ __launch_bounds__(256) void attn_kernel(
    const ushort_t* __restrict__ qw, const ushort_t* __restrict__ kw,
    const ushort_t* __restrict__ vtw, ushort_t* __restrict__ attn_out,
    const int* __restrict__ cs_ptr) {
  __shared__ __align__(16) ushort_t Ks[2 * 64 * 64];  // [buf][kpos][d], swizzled
  __shared__ __align__(16) ushort_t Vs[2 * 64 * 64];  // [buf][d][kpos], swizzled
  const int tid = threadIdx.x;
  const int lane = tid & 63;
  const int wave = tid >> 6;
  const int quad = lane >> 4, l16 = lane & 15;

  const int bid = blockIdx.x;
  const int bh = bid & 31;
  const int j = bid >> 5;
  const int i = j & 7, g = j >> 3;
  const int qt = (g == 0) ? i : (g == 1) ? (31 - i) : (g == 2) ? (8 + i) : (23 - i);
  const int b = bh >> 4, h = bh & 15;
  const int cs = cs_ptr[0];
  const size_t headP = (size_t)(b * 16 + h) * 2048 * 64;

  // ---- staging offsets (tile-local; chunk = 8 bf16 = 16B) ----
  // K: LDS chunk (tid&7) of row (s*32 + tid>>3) holds global chunk
  //    (tid&7) ^ f(row), f(row) = ((row>>3)&1) | ((row&3)<<1)  [octet-distinct]
  // V: LDS chunk (tid&7) of row (s*32 + tid>>3) holds global chunk
  //    (tid&7) ^ (row&7).
  int offk[2], offv[2];
#pragma unroll
  for (int s = 0; s < 2; ++s) {
    const int krow = s * 32 + (tid >> 3);
    const int f = ((krow >> 3) & 1) | ((krow & 3) << 1);
    offk[s] = krow * 64 + (((tid & 7) ^ f) << 3);
    const int vrow = s * 32 + (tid >> 3);
    const int vj = (tid & 7) ^ (vrow & 7);
    offv[s] = vrow * 2048 + vj * 8;
  }
  const ushort_t* kbase = kw + headP;
  const ushort_t* vbase = vtw + headP;
  ushort_t* lK = Ks + tid * 8;
  ushort_t* lV = Vs + tid * 8;

  // read-side swizzles: kswz = f(permuted row); row bits {0,1}=l16&3, bit3=(l16>>2)&1
  const int kswz = ((l16 >> 2) & 1) | ((l16 & 3) << 1);
  const int vswz = l16 & 7;
  const int lrow = ((l16 >> 2) << 3) + (l16 & 3);  // lane part of permuted K row

  int buf = 0;
  auto stage = [&](int bsel, int kt0) {
    ushort_t* dK = lK + bsel * 4096;
    ushort_t* dV = lV + bsel * 4096;
#pragma unroll
    for (int s = 0; s < 2; ++s)
      gl_lds16(kbase + (size_t)kt0 * 64 + offk[s], dK + s * 2048);
#pragma unroll
    for (int s = 0; s < 2; ++s)
      gl_lds16(vbase + kt0 + offv[s], dV + s * 2048);
  };

  const int q0 = qt * 64;
  const int wq0 = q0 + wave * 16;

  // Q as B-operand frags (pre-scaled by 0.125*log2e)
  short8 qf[2];
  {
    const int qrow = wq0 + l16;
    qf[0] = *(const short8*)(qw + headP + (size_t)qrow * 64 + quad * 8);
    qf[1] = *(const short8*)(qw + headP + (size_t)qrow * 64 + 32 + quad * 8);
  }

  floatx4 OT[4] = {};          // O^T: row d = di*16+quad*4+r, col q = l16
  float m_ = -1e30f, l_ = 0.f; // m_ row-uniform; l_ per-lane partial (exp2 dom.)

  const int kmax = min(1920, max(q0 + 64, cs));
  const int ntiles = (kmax + 63) >> 6;

  // prologue: stage tile 0 into buf 0
  stage(0, 0);
  __syncthreads();

  for (int t = 0; t < ntiles; ++t) {
    const int kt0 = t << 6;
    // prefetch next tile into the other buffer (hidden under compute)
    if (t + 1 < ntiles) stage(buf ^ 1, kt0 + 64);

    const bool active = !(kt0 > wq0 + 15 && kt0 >= cs);
    if (active) {
      const ushort_t* kb = Ks + buf * 4096;

      // S^T = K Q^T with permuted K rows: lane (quad,l16) ST[ni][r] is the
      // score of key k = kt0 + 32(ni&1) + 4(ni>>1) + 8*quad + r.
      floatx4 ST[4];
      __builtin_amdgcn_s_setprio(1);
#pragma unroll
      for (int ni = 0; ni < 4; ++ni) {
        const int nrow = ((ni & 1) << 5) + ((ni >> 1) << 2);
        const ushort_t* krow = kb + (nrow + lrow) * 64;
        short8 kf0 = *(const short8*)(krow + ((quad ^ kswz) << 3));
        short8 kf1 = *(const short8*)(krow + (((quad + 4) ^ kswz) << 3));
        floatx4 z = {};
        z = MFMA16(kf0, qf[0], z);
        ST[ni] = MFMA16(kf1, qf[1], z);
      }
      __builtin_amdgcn_s_setprio(0);

      if (kt0 + 63 > wq0) {  // diagonal straddle / tail: elementwise mask
        const int qq = wq0 + l16;
#pragma unroll
        for (int ni = 0; ni < 4; ++ni) {
          const int kb0 = kt0 + ((ni & 1) << 5) + ((ni >> 1) << 2) + (quad << 3);
#pragma unroll
          for (int r = 0; r < 4; ++r) {
            const int k = kb0 + r;
            if (!(k <= qq || k < cs)) ST[ni][r] = -1e30f;
          }
        }
      }

      // tile max (exp2 domain): max3-fused tree + 2 cross-quad shuffles
      float mt;
      {
        float t0 = fmaxf(fmaxf(ST[0][0], ST[0][1]), ST[0][2]);
        float t1 = fmaxf(fmaxf(ST[0][3], ST[1][0]), ST[1][1]);
        float t2 = fmaxf(fmaxf(ST[1][2], ST[1][3]), ST[2][0]);
        float t3 = fmaxf(fmaxf(ST[2][1], ST[2][2]), ST[2][3]);
        float t4 = fmaxf(fmaxf(ST[3][0], ST[3][1]), ST[3][2]);
        float u0 = fmaxf(fmaxf(t0, t1), t2);
        float u1 = fmaxf(fmaxf(t3, t4), ST[3][3]);
        mt = fmaxf(u0, u1);
      }
      mt = fmaxf(mt, __shfl_xor(mt, 16, 64));
      mt = fmaxf(mt, __shfl_xor(mt, 32, 64));
      // defer-max (T13): skip rescale when the whole wave's maxes are close
      if (!__all(mt <= m_ + 8.0f)) {
        const float mn = fmaxf(m_, mt);
        const float al = fexp2(m_ - mn);
        m_ = mn;
        l_ *= al;
#pragma unroll
        for (int di = 0; di < 4; ++di) OT[di] *= al;
      }
      // exp + per-lane partial sum (cross-quad sum deferred to epilogue:
      // al is row-uniform so the partial-sum recurrence is exact)
      float sub[4];
#pragma unroll
      for (int ni = 0; ni < 4; ++ni) {
        float p0 = fexp2(ST[ni][0] - m_);
        float p1 = fexp2(ST[ni][1] - m_);
        float p2 = fexp2(ST[ni][2] - m_);
        float p3 = fexp2(ST[ni][3] - m_);
        ST[ni][0] = p0; ST[ni][1] = p1; ST[ni][2] = p2; ST[ni][3] = p3;
        sub[ni] = (p0 + p1) + (p2 + p3);
      }
      l_ += (sub[0] + sub[1]) + (sub[2] + sub[3]);

      // O^T += V^T P^T : pb[s] is lane-local = [ST[s][0..3], ST[s+2][0..3]]
      const ushort_t* vb = Vs + buf * 4096;
#pragma unroll
      for (int s = 0; s < 2; ++s) {
        int d0, d1, d2, d3;
        asm("v_cvt_pk_bf16_f32 %0, %1, %2" : "=v"(d0) : "v"(ST[s][0]), "v"(ST[s][1]));
        asm("v_cvt_pk_bf16_f32 %0, %1, %2" : "=v"(d1) : "v"(ST[s][2]), "v"(ST[s][3]));
        asm("v_cvt_pk_bf16_f32 %0, %1, %2" : "=v"(d2) : "v"(ST[s + 2][0]), "v"(ST[s + 2][1]));
        asm("v_cvt_pk_bf16_f32 %0, %1, %2" : "=v"(d3) : "v"(ST[s + 2][2]), "v"(ST[s + 2][3]));
        union { int i[4]; short8 v; } u;
        u.i[0] = d0; u.i[1] = d1; u.i[2] = d2; u.i[3] = d3;
        const short8 pb = u.v;
        __builtin_amdgcn_s_setprio(1);
#pragma unroll
        for (int di = 0; di < 4; ++di) {
          const ushort_t* vrow = vb + (di * 16 + l16) * 64;
          short8 vf = *(const short8*)(vrow + ((((s << 2) + quad) ^ vswz) << 3));
          OT[di] = MFMA16(vf, pb, OT[di]);
        }
        __builtin_amdgcn_s_setprio(0);
      }
    }

    __syncthreads();  // staging of next tile complete + all readers done
    buf ^= 1;
  }

  // complete the deferred row-sum, normalize, store (8B per lane)
  l_ += __shfl_xor(l_, 16, 64);
  l_ += __shfl_xor(l_, 32, 64);
  const float inv = 1.f / l_;
  const int qq = wq0 + l16;
#pragma unroll
  for (int di = 0; di < 4; ++di) {
    ushort4v o4;
    o4.x = f2bf(OT[di][0] * inv);
    o4.y = f2bf(OT[di][1] * inv);
    o4.z = f2bf(OT[di][2] * inv);
    o4.w = f2bf(OT[di][3] * inv);
    *(ushort4v*)(attn_out + ((size_t)(b * 2048 + qq)) * 1024 + h * 64 +
                 di * 16 + quad * 4) = o4;
  }
}

// ---------------------------------------------------------------- launch
extern "C" void kernel_launch(void* const* d_in, const int* in_sizes, int n_in,
                              void* d_out, int out_size, void* d_ws, size_t ws_size,
                              hipStream_t stream) {
  const float* x      = (const float*)d_in[0];
  const int*   cs     = (const int*)d_in[2];
  const float* w_qkv  = (const float*)d_in[3];
  const float* w_proj = (const float*)d_in[4];
  const float* b_proj = (const float*)d_in[5];

  float* out     = (float*)d_out;
  float* present = out + (size_t)2 * 2048 * 1024;

  char* ws = (char*)d_ws;
  ushort_t* xb      = (ushort_t*)(ws);
  ushort_t* wqb     = (ushort_t*)(ws + ((size_t)8  << 20));
  ushort_t* wpb     = (ushort_t*)(ws + ((size_t)14 << 20));
  ushort_t* q_ws    = (ushort_t*)(ws + ((size_t)16 << 20));
  ushort_t* k_ws    = (ushort_t*)(ws + ((size_t)24 << 20));
  ushort_t* vT_ws   = (ushort_t*)(ws + ((size_t)32 << 20));
  ushort_t* attn_ws = (ushort_t*)(ws + ((size_t)40 << 20));

  // 8M elements total, 4/thread -> 8192 blocks exactly.
  cvt_all_kernel<<<8192, 256, 0, stream>>>(x, w_qkv, w_proj, xb, wqb, wpb);

  // gemm0: 32x24 tiles of 128x128, XCD rectangles 8tm x 12tn -> grid 768 (3/CU)
  gemm_bt<0, 128><<<768, 256, 0, stream>>>(xb, wqb, 1024, 12,
                                           nullptr, present, q_ws, k_ws, vT_ws, nullptr);

  attn_kernel<<<1024, 256, 0, stream>>>(q_ws, k_ws, vT_ws, attn_ws, cs);

  // gemm1: 32x16 tiles of 128x64, XCD rectangles 8tm x 8tn -> grid 512 (2/CU)
  gemm_bt<1, 64><<<512, 256, 0, stream>>>(attn_ws, wpb, 1024, 8,
                                          out, nullptr, nullptr, nullptr, nullptr, b_proj);
}

// Round 12
// 191.212 us; speedup vs baseline: 1.1376x; 1.1376x over previous
//
#include <hip/hip_runtime.h>

// ValleFlashAttention on MI355X (gfx950).
// B=2, N=2048, C=1024, H=16, hd=64. PAD_TAIL=128 (keys >= 1920 masked).
// causal_start read from d_in[2].
//
// Round 16:
//  - GEMMs: reverted byte-wise to R12's 2-phase double-buffered 128x128 form
//    (best measured: gemm0 ~46.5us, VGPR 76). R15's counted-vmcnt triple
//    buffer REGRESSED to 76us: asm "memory" clobbers + 3-buffer rotation
//    pushed VGPR to 104 and VALUBusy to 38% (address rematerialization) --
//    compiler-defeating wait asm, guide rule #5/#18.
//  - attn: softmax row-sum moved to the MFMA pipe. l = sum_k P[k][q] is
//    computed as MFMA16(ones, pb, lsum) (full cross-lane 32-k sum, exact):
//    2 MFMAs/tile on the 13%-utilized matrix pipe replace 16 v_add/tile +
//    2 epilogue shuffles on the 59%-utilized VALU pipe. l is now summed over
//    the same bf16 P that multiplies V (more self-consistent).
//  - attn keeps raw v_exp_f32 (R15).

typedef unsigned short ushort_t;
typedef short short8 __attribute__((ext_vector_type(8)));
typedef float floatx4 __attribute__((ext_vector_type(4)));
typedef unsigned short ushort4v __attribute__((ext_vector_type(4)));

#define MFMA16(a, b, c) __builtin_amdgcn_mfma_f32_16x16x32_bf16(a, b, c, 0, 0, 0)

__device__ __forceinline__ ushort_t f2bf(float f) {   // RNE
  unsigned int u = __float_as_uint(f);
  u += 0x7fffu + ((u >> 16) & 1u);
  return (ushort_t)(u >> 16);
}

__device__ __forceinline__ float fexp2(float x) {  // raw v_exp_f32 (exp2)
  float r;
  asm("v_exp_f32 %0, %1" : "=v"(r) : "v"(x));
  return r;
}

// async global->LDS, 16B per lane; LDS dest must be wave-uniform base + lane*16.
__device__ __forceinline__ void gl_lds16(const ushort_t* g, ushort_t* l) {
  __builtin_amdgcn_global_load_lds(
      (const __attribute__((address_space(1))) void*)g,
      (__attribute__((address_space(3))) void*)l, 16, 0, 0);
}

// ---------------------------------------------------------------- cvt fp32->bf16
__global__ __launch_bounds__(256) void cvt_all_kernel(
    const float* __restrict__ x, const float* __restrict__ wq,
    const float* __restrict__ wp, ushort_t* __restrict__ xb,
    ushort_t* __restrict__ wqb, ushort_t* __restrict__ wpb) {
  int i = (blockIdx.x * 256 + threadIdx.x) * 4;
  const float* s;
  ushort_t* d;
  int off;
  if (i < (4 << 20)) {            // x: 4096*1024
    s = x; d = xb; off = i;
  } else if (i < (7 << 20)) {     // w_qkv: 3072*1024
    s = wq; d = wqb; off = i - (4 << 20);
  } else {                        // w_proj: 1024*1024
    s = wp; d = wpb; off = i - (7 << 20);
  }
  float4 v = *(const float4*)(s + off);
  ushort4v o;
  o.x = f2bf(v.x); o.y = f2bf(v.y); o.z = f2bf(v.z); o.w = f2bf(v.w);
  *(ushort4v*)(d + off) = o;
}

// ---------------------------------------------------------------- GEMM (B^T form)
// C[m][n] = sum_k A[m][k] * Bm[n][k].  128x128 tile, BK=32, 4 waves of 64x64.
// 2-phase double-buffered. 2D XCD rectangles: xcd=bid&7 owns 8 tm x TNC tn
// tiles (tm-inner order). Grid must be 8 * 8 * TNC.
template <int EPI>
__global__ __launch_bounds__(256) void gemm_bt(
    const ushort_t* __restrict__ A, const ushort_t* __restrict__ Bm,
    int K, int TNC,
    float* __restrict__ outf, float* __restrict__ present,
    ushort_t* __restrict__ q_ws, ushort_t* __restrict__ k_ws,
    ushort_t* __restrict__ vT_ws, const float* __restrict__ b_proj) {
  __shared__ __align__(16) ushort_t As[2 * 128 * 32];
  __shared__ __align__(16) ushort_t Bs[2 * 128 * 32];
  const int tid = threadIdx.x;
  const int wave = tid >> 6, lane = tid & 63;
  const int quad = lane >> 4, l16 = lane & 15;
  const int wm = wave >> 1, wn = wave & 1;
  // 2D XCD rectangle mapping (tm-inner)
  const int xcd = blockIdx.x & 7;
  const int loc = blockIdx.x >> 3;
  const int tm = (xcd >> 1) * 8 + (loc & 7);
  const int tn = (xcd & 1) * TNC + (loc >> 3);

  const int r0 = tid >> 2, c0 = (tid & 3) * 8;
  const int r1 = r0 + 64;
  const ushort_t* a0 = A + (size_t)(tm * 128 + r0) * K + c0;
  const ushort_t* a1 = A + (size_t)(tm * 128 + r1) * K + c0;
  const ushort_t* b0 = Bm + (size_t)(tn * 128 + r0) * K + c0;
  const ushort_t* b1 = Bm + (size_t)(tn * 128 + r1) * K + c0;
  ushort_t* lA0 = As + tid * 8;
  ushort_t* lA1 = As + (tid + 256) * 8;
  ushort_t* lB0 = Bs + tid * 8;
  ushort_t* lB1 = Bs + (tid + 256) * 8;

  auto stage = [&](int bsel, int k0) {
    const int lo = bsel * 4096;
    gl_lds16(a0 + k0, lA0 + lo);
    gl_lds16(a1 + k0, lA1 + lo);
    gl_lds16(b0 + k0, lB0 + lo);
    gl_lds16(b1 + k0, lB1 + lo);
  };

  floatx4 acc[4][4] = {};

  stage(0, 0);
  __syncthreads();
  int buf = 0;

  for (int k0 = 0; k0 < K; k0 += 32) {
    if (k0 + 32 < K) stage(buf ^ 1, k0 + 32);  // prefetch hides under compute
    const ushort_t* as = As + buf * 4096;
    const ushort_t* bs = Bs + buf * 4096;
    short8 af[4], bfr[4];
#pragma unroll
    for (int mi = 0; mi < 4; ++mi)
      af[mi] = *(const short8*)(as + (wm * 64 + mi * 16 + l16) * 32 + quad * 8);
#pragma unroll
    for (int ni = 0; ni < 4; ++ni)
      bfr[ni] = *(const short8*)(bs + (wn * 64 + ni * 16 + l16) * 32 + quad * 8);
#pragma unroll
    for (int mi = 0; mi < 4; ++mi)
#pragma unroll
      for (int ni = 0; ni < 4; ++ni)
        acc[mi][ni] = MFMA16(af[mi], bfr[ni], acc[mi][ni]);
    __syncthreads();  // prefetch complete (vmcnt) + all readers done
    buf ^= 1;
  }

#pragma unroll
  for (int mi = 0; mi < 4; ++mi) {
#pragma unroll
    for (int ni = 0; ni < 4; ++ni) {
      const int gm0 = tm * 128 + wm * 64 + mi * 16 + quad * 4;
      const int gn = tn * 128 + wn * 64 + ni * 16 + l16;
      if constexpr (EPI == 0) {
        const int b = gm0 >> 11, pos0 = gm0 & 2047;
        const int which = gn >> 10, rem = gn & 1023;
        const int h = rem >> 6, d = rem & 63;
        const size_t hb = (size_t)(b * 16 + h);
        if (which == 0) {
          // Q pre-scaled by hd^-0.5 * log2(e) so softmax runs in exp2 domain.
#pragma unroll
          for (int r = 0; r < 4; ++r)
            q_ws[(hb * 2048 + pos0 + r) * 64 + d] =
                f2bf(acc[mi][ni][r] * 0.1803368867f);
        } else if (which == 1) {
#pragma unroll
          for (int r = 0; r < 4; ++r) {
            size_t pk = (hb * 2048 + pos0 + r) * 64 + d;
            present[pk] = acc[mi][ni][r];
            k_ws[pk] = f2bf(acc[mi][ni][r]);
          }
        } else {
#pragma unroll
          for (int r = 0; r < 4; ++r)
            present[((size_t)((2 + b) * 16 + h) * 2048 + pos0 + r) * 64 + d] =
                acc[mi][ni][r];
          ushort4v pk4;
          pk4.x = f2bf(acc[mi][ni][0]); pk4.y = f2bf(acc[mi][ni][1]);
          pk4.z = f2bf(acc[mi][ni][2]); pk4.w = f2bf(acc[mi][ni][3]);
          *(ushort4v*)(vT_ws + (hb * 64 + d) * 2048 + pos0) = pk4;
        }
      } else {
#pragma unroll
        for (int r = 0; r < 4; ++r)
          outf[(size_t)(gm0 + r) * 1024 + gn] = acc[mi][ni][r] + b_proj[gn];
      }
    }
  }
}

// ---------------------------------------------------------------- flash attention
// grid = 1024: bid -> bh = bid&31; j = bid>>5, i = j&7, g = j>>3,
// qt = {i, 31-i, 8+i, 23-i}[g]  (per-CU tile-load == 66 for every CU under
// round-robin dispatch with all 4 blocks/CU resident).
// One 64-row q-tile per block, 4 waves x 16 q-rows. BK=64, K/V double-buffered,
// 1 barrier/tile. LDS 32 KB -> 4 blocks/CU. Permuted K rows make each lane's
// scores exactly the PV B-fragment (no P LDS round-trip). Row-sum l via
// MFMA with a ones A-operand (idle matrix pipe, no shuffles).
__global__ __launch_bounds__(256) void attn_kernel(
    const ushort_t* __restrict__ qw, const ushort_t* __restrict__ kw,
    const ushort_t* __restrict__ vtw, ushort_t* __restrict__ attn_out,
    const int* __restrict__ cs_ptr) {
  __shared__ __align__(16) ushort_t Ks[2 * 64 * 64];  // [buf][kpos][d], swizzled
  __shared__ __align__(16) ushort_t Vs[2 * 64 * 64];  // [buf][d][kpos], swizzled
  const int tid = threadIdx.x;
  const int lane = tid & 63;
  const int wave = tid >> 6;
  const int quad = lane >> 4, l16 = lane & 15;

  const int bid = blockIdx.x;
  const int bh = bid & 31;
  const int j = bid >> 5;
  const int i = j & 7, g = j >> 3;
  const int qt = (g == 0) ? i : (g == 1) ? (31 - i) : (g == 2) ? (8 + i) : (23 - i);
  const int b = bh >> 4, h = bh & 15;
  const int cs = cs_ptr[0];
  const size_t headP = (size_t)(b * 16 + h) * 2048 * 64;

  // ---- staging offsets (tile-local; chunk = 8 bf16 = 16B) ----
  // K: LDS chunk (tid&7) of row (s*32 + tid>>3) holds global chunk
  //    (tid&7) ^ f(row), f(row) = ((row>>3)&1) | ((row&3)<<1)  [octet-distinct]
  // V: LDS chunk (tid&7) of row (s*32 + tid>>3) holds global chunk
  //    (tid&7) ^ (row&7).
  int offk[2], offv[2];
#pragma unroll
  for (int s = 0; s < 2; ++s) {
    const int krow = s * 32 + (tid >> 3);
    const int f = ((krow >> 3) & 1) | ((krow & 3) << 1);
    offk[s] = krow * 64 + (((tid & 7) ^ f) << 3);
    const int vrow = s * 32 + (tid >> 3);
    const int vj = (tid & 7) ^ (vrow & 7);
    offv[s] = vrow * 2048 + vj * 8;
  }
  const ushort_t* kbase = kw + headP;
  const ushort_t* vbase = vtw + headP;
  ushort_t* lK = Ks + tid * 8;
  ushort_t* lV = Vs + tid * 8;

  // read-side swizzles: kswz = f(permuted row); row bits {0,1}=l16&3, bit3=(l16>>2)&1
  const int kswz = ((l16 >> 2) & 1) | ((l16 & 3) << 1);
  const int vswz = l16 & 7;
  const int lrow = ((l16 >> 2) << 3) + (l16 & 3);  // lane part of permuted K row

  int buf = 0;
  auto stage = [&](int bsel, int kt0) {
    ushort_t* dK = lK + bsel * 4096;
    ushort_t* dV = lV + bsel * 4096;
#pragma unroll
    for (int s = 0; s < 2; ++s)
      gl_lds16(kbase + (size_t)kt0 * 64 + offk[s], dK + s * 2048);
#pragma unroll
    for (int s = 0; s < 2; ++s)
      gl_lds16(vbase + kt0 + offv[s], dV + s * 2048);
  };

  const int q0 = qt * 64;
  const int wq0 = q0 + wave * 16;

  // Q as B-operand frags (pre-scaled by 0.125*log2e)
  short8 qf[2];
  {
    const int qrow = wq0 + l16;
    qf[0] = *(const short8*)(qw + headP + (size_t)qrow * 64 + quad * 8);
    qf[1] = *(const short8*)(qw + headP + (size_t)qrow * 64 + 32 + quad * 8);
  }

  // all-ones bf16 A-fragment for the l-sum MFMA
  const short8 ones8 = {(short)0x3F80, (short)0x3F80, (short)0x3F80, (short)0x3F80,
                        (short)0x3F80, (short)0x3F80, (short)0x3F80, (short)0x3F80};

  floatx4 OT[4] = {};     // O^T: row d = di*16+quad*4+r, col q = l16
  floatx4 lsum = {};      // lsum[r] (all r equal) = sum_k P[k][q=l16], via MFMA
  float m_ = -1e30f;      // running max, row-uniform (exp2 domain)

  const int kmax = min(1920, max(q0 + 64, cs));
  const int ntiles = (kmax + 63) >> 6;

  // prologue: stage tile 0 into buf 0
  stage(0, 0);
  __syncthreads();

  for (int t = 0; t < ntiles; ++t) {
    const int kt0 = t << 6;
    // prefetch next tile into the other buffer (hidden under compute)
    if (t + 1 < ntiles) stage(buf ^ 1, kt0 + 64);

    const bool active = !(kt0 > wq0 + 15 && kt0 >= cs);
    if (active) {
      const ushort_t* kb = Ks + buf * 4096;

      // S^T = K Q^T with permuted K rows: lane (quad,l16) ST[ni][r] is the
      // score of key k = kt0 + 32(ni&1) + 4(ni>>1) + 8*quad + r.
      floatx4 ST[4];
      __builtin_amdgcn_s_setprio(1);
#pragma unroll
      for (int ni = 0; ni < 4; ++ni) {
        const int nrow = ((ni & 1) << 5) + ((ni >> 1) << 2);
        const ushort_t* krow = kb + (nrow + lrow) * 64;
        short8 kf0 = *(const short8*)(krow + ((quad ^ kswz) << 3));
        short8 kf1 = *(const short8*)(krow + (((quad + 4) ^ kswz) << 3));
        floatx4 z = {};
        z = MFMA16(kf0, qf[0], z);
        ST[ni] = MFMA16(kf1, qf[1], z);
      }
      __builtin_amdgcn_s_setprio(0);

      if (kt0 + 63 > wq0) {  // diagonal straddle / tail: elementwise mask
        const int qq = wq0 + l16;
#pragma unroll
        for (int ni = 0; ni < 4; ++ni) {
          const int kb0 = kt0 + ((ni & 1) << 5) + ((ni >> 1) << 2) + (quad << 3);
#pragma unroll
          for (int r = 0; r < 4; ++r) {
            const int k = kb0 + r;
            if (!(k <= qq || k < cs)) ST[ni][r] = -1e30f;
          }
        }
      }

      // tile max (exp2 domain): max3-fused tree + 2 cross-quad shuffles
      float mt;
      {
        float t0 = fmaxf(fmaxf(ST[0][0], ST[0][1]), ST[0][2]);
        float t1 = fmaxf(fmaxf(ST[0][3], ST[1][0]), ST[1][1]);
        float t2 = fmaxf(fmaxf(ST[1][2], ST[1][3]), ST[2][0]);
        float t3 = fmaxf(fmaxf(ST[2][1], ST[2][2]), ST[2][3]);
        float t4 = fmaxf(fmaxf(ST[3][0], ST[3][1]), ST[3][2]);
        float u0 = fmaxf(fmaxf(t0, t1), t2);
        float u1 = fmaxf(fmaxf(t3, t4), ST[3][3]);
        mt = fmaxf(u0, u1);
      }
      mt = fmaxf(mt, __shfl_xor(mt, 16, 64));
      mt = fmaxf(mt, __shfl_xor(mt, 32, 64));
      // defer-max (T13): skip rescale when the whole wave's maxes are close
      if (!__all(mt <= m_ + 8.0f)) {
        const float mn = fmaxf(m_, mt);
        const float al = fexp2(m_ - mn);
        m_ = mn;
        lsum *= al;
#pragma unroll
        for (int di = 0; di < 4; ++di) OT[di] *= al;
      }
      // exp (raw v_exp_f32); row-sum is done on the MFMA pipe below
#pragma unroll
      for (int ni = 0; ni < 4; ++ni) {
        ST[ni][0] = fexp2(ST[ni][0] - m_);
        ST[ni][1] = fexp2(ST[ni][1] - m_);
        ST[ni][2] = fexp2(ST[ni][2] - m_);
        ST[ni][3] = fexp2(ST[ni][3] - m_);
      }

      // O^T += V^T P^T ; lsum += 1^T P^T (ones-MFMA row-sum).
      // pb[s] is lane-local = [ST[s][0..3], ST[s+2][0..3]]
      const ushort_t* vb = Vs + buf * 4096;
#pragma unroll
      for (int s = 0; s < 2; ++s) {
        int d0, d1, d2, d3;
        asm("v_cvt_pk_bf16_f32 %0, %1, %2" : "=v"(d0) : "v"(ST[s][0]), "v"(ST[s][1]));
        asm("v_cvt_pk_bf16_f32 %0, %1, %2" : "=v"(d1) : "v"(ST[s][2]), "v"(ST[s][3]));
        asm("v_cvt_pk_bf16_f32 %0, %1, %2" : "=v"(d2) : "v"(ST[s + 2][0]), "v"(ST[s + 2][1]));
        asm("v_cvt_pk_bf16_f32 %0, %1, %2" : "=v"(d3) : "v"(ST[s + 2][2]), "v"(ST[s + 2][3]));
        union { int i[4]; short8 v; } u;
        u.i[0] = d0; u.i[1] = d1; u.i[2] = d2; u.i[3] = d3;
        const short8 pb = u.v;
        __builtin_amdgcn_s_setprio(1);
#pragma unroll
        for (int di = 0; di < 4; ++di) {
          const ushort_t* vrow = vb + (di * 16 + l16) * 64;
          short8 vf = *(const short8*)(vrow + ((((s << 2) + quad) ^ vswz) << 3));
          OT[di] = MFMA16(vf, pb, OT[di]);
        }
        lsum = MFMA16(ones8, pb, lsum);  // D[m][q] = sum_k P[k][q], all m equal
        __builtin_amdgcn_s_setprio(0);
      }
    }

    __syncthreads();  // staging of next tile complete + all readers done
    buf ^= 1;
  }

  // normalize (lsum[0] is the full row-sum; no shuffles needed), store
  const float inv = 1.f / lsum[0];
  const int qq = wq0 + l16;
#pragma unroll
  for (int di = 0; di < 4; ++di) {
    ushort4v o4;
    o4.x = f2bf(OT[di][0] * inv);
    o4.y = f2bf(OT[di][1] * inv);
    o4.z = f2bf(OT[di][2] * inv);
    o4.w = f2bf(OT[di][3] * inv);
    *(ushort4v*)(attn_out + ((size_t)(b * 2048 + qq)) * 1024 + h * 64 +
                 di * 16 + quad * 4) = o4;
  }
}

// ---------------------------------------------------------------- launch
extern "C" void kernel_launch(void* const* d_in, const int* in_sizes, int n_in,
                              void* d_out, int out_size, void* d_ws, size_t ws_size,
                              hipStream_t stream) {
  const float* x      = (const float*)d_in[0];
  const int*   cs     = (const int*)d_in[2];
  const float* w_qkv  = (const float*)d_in[3];
  const float* w_proj = (const float*)d_in[4];
  const float* b_proj = (const float*)d_in[5];

  float* out     = (float*)d_out;
  float* present = out + (size_t)2 * 2048 * 1024;

  char* ws = (char*)d_ws;
  ushort_t* xb      = (ushort_t*)(ws);
  ushort_t* wqb     = (ushort_t*)(ws + ((size_t)8  << 20));
  ushort_t* wpb     = (ushort_t*)(ws + ((size_t)14 << 20));
  ushort_t* q_ws    = (ushort_t*)(ws + ((size_t)16 << 20));
  ushort_t* k_ws    = (ushort_t*)(ws + ((size_t)24 << 20));
  ushort_t* vT_ws   = (ushort_t*)(ws + ((size_t)32 << 20));
  ushort_t* attn_ws = (ushort_t*)(ws + ((size_t)40 << 20));

  // 8M elements total, 4/thread -> 8192 blocks exactly.
  cvt_all_kernel<<<8192, 256, 0, stream>>>(x, w_qkv, w_proj, xb, wqb, wpb);

  // gemm0: 32x24 tiles of 128x128, XCD rectangles 8tm x 12tn -> grid 768
  gemm_bt<0><<<768, 256, 0, stream>>>(xb, wqb, 1024, 12,
                                      nullptr, present, q_ws, k_ws, vT_ws, nullptr);

  attn_kernel<<<1024, 256, 0, stream>>>(q_ws, k_ws, vT_ws, attn_ws, cs);

  // gemm1: 32x8 tiles of 128x128, XCD rectangles 8tm x 4tn -> grid 256
  gemm_bt<1><<<256, 256, 0, stream>>>(attn_ws, wpb, 1024, 4,
                                      out, nullptr, nullptr, nullptr, nullptr, b_proj);
}

// Round 13
// 187.169 us; speedup vs baseline: 1.1622x; 1.0216x over previous
//
#include <hip/hip_runtime.h>

// ValleFlashAttention on MI355X (gfx950).
// B=2, N=2048, C=1024, H=16, hd=64. PAD_TAIL=128 (keys >= 1920 masked).
// causal_start read from d_in[2].
//
// Round 17:
//  - gemm1: 128x64 tiles, grid 512 = 2 blocks/CU (was 128x128 grid 256 =
//    1 block/CU, 1 wave/SIMD -> fully latency-exposed; never in top-5 but
//    bounded only < 45us; R13 validated this geometry).
//  - gemm0: tn-INNER XCD-rectangle order. tm-inner's hot set was A 2MB +
//    B 3MB = 5MB > 4MB L2 (FETCH 20.6MB); tn-inner holds ONE A panel
//    (256KB) + 12 B panels (3MB) = 3.25MB < 4MB -> B L2-resident across
//    all 8 tm sweeps.
//  - attn: byte-identical to R16 (45.1 us: ones-MFMA row-sum, v_exp_f32,
//    octet-distinct K swizzle, balanced qt map).

typedef unsigned short ushort_t;
typedef short short8 __attribute__((ext_vector_type(8)));
typedef float floatx4 __attribute__((ext_vector_type(4)));
typedef unsigned short ushort4v __attribute__((ext_vector_type(4)));

#define MFMA16(a, b, c) __builtin_amdgcn_mfma_f32_16x16x32_bf16(a, b, c, 0, 0, 0)

__device__ __forceinline__ ushort_t f2bf(float f) {   // RNE
  unsigned int u = __float_as_uint(f);
  u += 0x7fffu + ((u >> 16) & 1u);
  return (ushort_t)(u >> 16);
}

__device__ __forceinline__ float fexp2(float x) {  // raw v_exp_f32 (exp2)
  float r;
  asm("v_exp_f32 %0, %1" : "=v"(r) : "v"(x));
  return r;
}

// async global->LDS, 16B per lane; LDS dest must be wave-uniform base + lane*16.
__device__ __forceinline__ void gl_lds16(const ushort_t* g, ushort_t* l) {
  __builtin_amdgcn_global_load_lds(
      (const __attribute__((address_space(1))) void*)g,
      (__attribute__((address_space(3))) void*)l, 16, 0, 0);
}

// ---------------------------------------------------------------- cvt fp32->bf16
__global__ __launch_bounds__(256) void cvt_all_kernel(
    const float* __restrict__ x, const float* __restrict__ wq,
    const float* __restrict__ wp, ushort_t* __restrict__ xb,
    ushort_t* __restrict__ wqb, ushort_t* __restrict__ wpb) {
  int i = (blockIdx.x * 256 + threadIdx.x) * 4;
  const float* s;
  ushort_t* d;
  int off;
  if (i < (4 << 20)) {            // x: 4096*1024
    s = x; d = xb; off = i;
  } else if (i < (7 << 20)) {     // w_qkv: 3072*1024
    s = wq; d = wqb; off = i - (4 << 20);
  } else {                        // w_proj: 1024*1024
    s = wp; d = wpb; off = i - (7 << 20);
  }
  float4 v = *(const float4*)(s + off);
  ushort4v o;
  o.x = f2bf(v.x); o.y = f2bf(v.y); o.z = f2bf(v.z); o.w = f2bf(v.w);
  *(ushort4v*)(d + off) = o;
}

// ---------------------------------------------------------------- GEMM (B^T form)
// C[m][n] = sum_k A[m][k] * Bm[n][k].  128xNT tile, BK=32, 4 waves.
// 2-phase double-buffered. 2D XCD rectangles, tn-INNER order: xcd=bid&7 owns
// 8 tm x TNC tn tiles; consecutive blocks sweep tn (one hot A panel + TNC
// B panels resident in L2). Grid = 8 * 8 * TNC.
template <int EPI, int NT>
__global__ __launch_bounds__(256) void gemm_bt(
    const ushort_t* __restrict__ A, const ushort_t* __restrict__ Bm,
    int K, int TNC,
    float* __restrict__ outf, float* __restrict__ present,
    ushort_t* __restrict__ q_ws, ushort_t* __restrict__ k_ws,
    ushort_t* __restrict__ vT_ws, const float* __restrict__ b_proj) {
  constexpr int ABUF = 128 * 32;   // ushorts per A buffer
  constexpr int BBUF = NT * 32;    // ushorts per B buffer
  constexpr int BNF = NT / 32;     // B fragments per wave
  __shared__ __align__(16) ushort_t As[2 * ABUF];
  __shared__ __align__(16) ushort_t Bs[2 * BBUF];
  const int tid = threadIdx.x;
  const int wave = tid >> 6, lane = tid & 63;
  const int quad = lane >> 4, l16 = lane & 15;
  const int wm = wave >> 1, wn = wave & 1;
  // 2D XCD rectangle mapping, tn-inner
  const int xcd = blockIdx.x & 7;
  const int loc = blockIdx.x >> 3;
  const int tm = (xcd >> 1) * 8 + (loc / TNC);
  const int tn = (xcd & 1) * TNC + (loc % TNC);

  const int r0 = tid >> 2, c0 = (tid & 3) * 8;
  const int r1 = r0 + 64;
  const ushort_t* a0 = A + (size_t)(tm * 128 + r0) * K + c0;
  const ushort_t* a1 = A + (size_t)(tm * 128 + r1) * K + c0;
  const ushort_t* b0 = Bm + (size_t)(tn * NT + r0) * K + c0;
  const ushort_t* b1 = (NT == 128) ? Bm + (size_t)(tn * NT + r1) * K + c0 : Bm;
  ushort_t* lA0 = As + tid * 8;
  ushort_t* lA1 = As + (tid + 256) * 8;
  ushort_t* lB0 = Bs + tid * 8;
  ushort_t* lB1 = Bs + (tid + 256) * 8;

  auto stage = [&](int bsel, int k0) {
    gl_lds16(a0 + k0, lA0 + bsel * ABUF);
    gl_lds16(a1 + k0, lA1 + bsel * ABUF);
    gl_lds16(b0 + k0, lB0 + bsel * BBUF);
    if constexpr (NT == 128) gl_lds16(b1 + k0, lB1 + bsel * BBUF);
  };

  floatx4 acc[4][BNF] = {};

  stage(0, 0);
  __syncthreads();
  int buf = 0;

  for (int k0 = 0; k0 < K; k0 += 32) {
    if (k0 + 32 < K) stage(buf ^ 1, k0 + 32);  // prefetch hides under compute
    const ushort_t* as = As + buf * ABUF;
    const ushort_t* bs = Bs + buf * BBUF;
    short8 af[4], bfr[BNF];
#pragma unroll
    for (int mi = 0; mi < 4; ++mi)
      af[mi] = *(const short8*)(as + (wm * 64 + mi * 16 + l16) * 32 + quad * 8);
#pragma unroll
    for (int ni = 0; ni < BNF; ++ni)
      bfr[ni] = *(const short8*)(bs + (wn * (NT / 2) + ni * 16 + l16) * 32 + quad * 8);
#pragma unroll
    for (int mi = 0; mi < 4; ++mi)
#pragma unroll
      for (int ni = 0; ni < BNF; ++ni)
        acc[mi][ni] = MFMA16(af[mi], bfr[ni], acc[mi][ni]);
    __syncthreads();  // prefetch complete (vmcnt) + all readers done
    buf ^= 1;
  }

#pragma unroll
  for (int mi = 0; mi < 4; ++mi) {
#pragma unroll
    for (int ni = 0; ni < BNF; ++ni) {
      const int gm0 = tm * 128 + wm * 64 + mi * 16 + quad * 4;
      const int gn = tn * NT + wn * (NT / 2) + ni * 16 + l16;
      if constexpr (EPI == 0) {
        const int b = gm0 >> 11, pos0 = gm0 & 2047;
        const int which = gn >> 10, rem = gn & 1023;
        const int h = rem >> 6, d = rem & 63;
        const size_t hb = (size_t)(b * 16 + h);
        if (which == 0) {
          // Q pre-scaled by hd^-0.5 * log2(e) so softmax runs in exp2 domain.
#pragma unroll
          for (int r = 0; r < 4; ++r)
            q_ws[(hb * 2048 + pos0 + r) * 64 + d] =
                f2bf(acc[mi][ni][r] * 0.1803368867f);
        } else if (which == 1) {
#pragma unroll
          for (int r = 0; r < 4; ++r) {
            size_t pk = (hb * 2048 + pos0 + r) * 64 + d;
            present[pk] = acc[mi][ni][r];
            k_ws[pk] = f2bf(acc[mi][ni][r]);
          }
        } else {
#pragma unroll
          for (int r = 0; r < 4; ++r)
            present[((size_t)((2 + b) * 16 + h) * 2048 + pos0 + r) * 64 + d] =
                acc[mi][ni][r];
          ushort4v pk4;
          pk4.x = f2bf(acc[mi][ni][0]); pk4.y = f2bf(acc[mi][ni][1]);
          pk4.z = f2bf(acc[mi][ni][2]); pk4.w = f2bf(acc[mi][ni][3]);
          *(ushort4v*)(vT_ws + (hb * 64 + d) * 2048 + pos0) = pk4;
        }
      } else {
#pragma unroll
        for (int r = 0; r < 4; ++r)
          outf[(size_t)(gm0 + r) * 1024 + gn] = acc[mi][ni][r] + b_proj[gn];
      }
    }
  }
}

// ---------------------------------------------------------------- flash attention
// grid = 1024: bid -> bh = bid&31; j = bid>>5, i = j&7, g = j>>3,
// qt = {i, 31-i, 8+i, 23-i}[g]  (per-CU tile-load == 66 for every CU under
// round-robin dispatch with all 4 blocks/CU resident).
// One 64-row q-tile per block, 4 waves x 16 q-rows. BK=64, K/V double-buffered,
// 1 barrier/tile. LDS 32 KB -> 4 blocks/CU. Permuted K rows make each lane's
// scores exactly the PV B-fragment (no P LDS round-trip). Row-sum l via
// MFMA with a ones A-operand (idle matrix pipe, no shuffles).
__global__ __launch_bounds__(256) void attn_kernel(
    const ushort_t* __restrict__ qw, const ushort_t* __restrict__ kw,
    const ushort_t* __restrict__ vtw, ushort_t* __restrict__ attn_out,
    const int* __restrict__ cs_ptr) {
  __shared__ __align__(16) ushort_t Ks[2 * 64 * 64];  // [buf][kpos][d], swizzled
  __shared__ __align__(16) ushort_t Vs[2 * 64 * 64];  // [buf][d][kpos], swizzled
  const int tid = threadIdx.x;
  const int lane = tid & 63;
  const int wave = tid >> 6;
  const int quad = lane >> 4, l16 = lane & 15;

  const int bid = blockIdx.x;
  const int bh = bid & 31;
  const int j = bid >> 5;
  const int i = j & 7, g = j >> 3;
  const int qt = (g == 0) ? i : (g == 1) ? (31 - i) : (g == 2) ? (8 + i) : (23 - i);
  const int b = bh >> 4, h = bh & 15;
  const int cs = cs_ptr[0];
  const size_t headP = (size_t)(b * 16 + h) * 2048 * 64;

  // ---- staging offsets (tile-local; chunk = 8 bf16 = 16B) ----
  // K: LDS chunk (tid&7) of row (s*32 + tid>>3) holds global chunk
  //    (tid&7) ^ f(row), f(row) = ((row>>3)&1) | ((row&3)<<1)  [octet-distinct]
  // V: LDS chunk (tid&7) of row (s*32 + tid>>3) holds global chunk
  //    (tid&7) ^ (row&7).
  int offk[2], offv[2];
#pragma unroll
  for (int s = 0; s < 2; ++s) {
    const int krow = s * 32 + (tid >> 3);
    const int f = ((krow >> 3) & 1) | ((krow & 3) << 1);
    offk[s] = krow * 64 + (((tid & 7) ^ f) << 3);
    const int vrow = s * 32 + (tid >> 3);
    const int vj = (tid & 7) ^ (vrow & 7);
    offv[s] = vrow * 2048 + vj * 8;
  }
  const ushort_t* kbase = kw + headP;
  const ushort_t* vbase = vtw + headP;
  ushort_t* lK = Ks + tid * 8;
  ushort_t* lV = Vs + tid * 8;

  // read-side swizzles: kswz = f(permuted row); row bits {0,1}=l16&3, bit3=(l16>>2)&1
  const int kswz = ((l16 >> 2) & 1) | ((l16 & 3) << 1);
  const int vswz = l16 & 7;
  const int lrow = ((l16 >> 2) << 3) + (l16 & 3);  // lane part of permuted K row

  int buf = 0;
  auto stage = [&](int bsel, int kt0) {
    ushort_t* dK = lK + bsel * 4096;
    ushort_t* dV = lV + bsel * 4096;
#pragma unroll
    for (int s = 0; s < 2; ++s)
      gl_lds16(kbase + (size_t)kt0 * 64 + offk[s], dK + s * 2048);
#pragma unroll
    for (int s = 0; s < 2; ++s)
      gl_lds16(vbase + kt0 + offv[s], dV + s * 2048);
  };

  const int q0 = qt * 64;
  const int wq0 = q0 + wave * 16;

  // Q as B-operand frags (pre-scaled by 0.125*log2e)
  short8 qf[2];
  {
    const int qrow = wq0 + l16;
    qf[0] = *(const short8*)(qw + headP + (size_t)qrow * 64 + quad * 8);
    qf[1] = *(const short8*)(qw + headP + (size_t)qrow * 64 + 32 + quad * 8);
  }

  // all-ones bf16 A-fragment for the l-sum MFMA
  const short8 ones8 = {(short)0x3F80, (short)0x3F80, (short)0x3F80, (short)0x3F80,
                        (short)0x3F80, (short)0x3F80, (short)0x3F80, (short)0x3F80};

  floatx4 OT[4] = {};     // O^T: row d = di*16+quad*4+r, col q = l16
  floatx4 lsum = {};      // lsum[r] (all r equal) = sum_k P[k][q=l16], via MFMA
  float m_ = -1e30f;      // running max, row-uniform (exp2 domain)

  const int kmax = min(1920, max(q0 + 64, cs));
  const int ntiles = (kmax + 63) >> 6;

  // prologue: stage tile 0 into buf 0
  stage(0, 0);
  __syncthreads();

  for (int t = 0; t < ntiles; ++t) {
    const int kt0 = t << 6;
    // prefetch next tile into the other buffer (hidden under compute)
    if (t + 1 < ntiles) stage(buf ^ 1, kt0 + 64);

    const bool active = !(kt0 > wq0 + 15 && kt0 >= cs);
    if (active) {
      const ushort_t* kb = Ks + buf * 4096;

      // S^T = K Q^T with permuted K rows: lane (quad,l16) ST[ni][r] is the
      // score of key k = kt0 + 32(ni&1) + 4(ni>>1) + 8*quad + r.
      floatx4 ST[4];
      __builtin_amdgcn_s_setprio(1);
#pragma unroll
      for (int ni = 0; ni < 4; ++ni) {
        const int nrow = ((ni & 1) << 5) + ((ni >> 1) << 2);
        const ushort_t* krow = kb + (nrow + lrow) * 64;
        short8 kf0 = *(const short8*)(krow + ((quad ^ kswz) << 3));
        short8 kf1 = *(const short8*)(krow + (((quad + 4) ^ kswz) << 3));
        floatx4 z = {};
        z = MFMA16(kf0, qf[0], z);
        ST[ni] = MFMA16(kf1, qf[1], z);
      }
      __builtin_amdgcn_s_setprio(0);

      if (kt0 + 63 > wq0) {  // diagonal straddle / tail: elementwise mask
        const int qq = wq0 + l16;
#pragma unroll
        for (int ni = 0; ni < 4; ++ni) {
          const int kb0 = kt0 + ((ni & 1) << 5) + ((ni >> 1) << 2) + (quad << 3);
#pragma unroll
          for (int r = 0; r < 4; ++r) {
            const int k = kb0 + r;
            if (!(k <= qq || k < cs)) ST[ni][r] = -1e30f;
          }
        }
      }

      // tile max (exp2 domain): max3-fused tree + 2 cross-quad shuffles
      float mt;
      {
        float t0 = fmaxf(fmaxf(ST[0][0], ST[0][1]), ST[0][2]);
        float t1 = fmaxf(fmaxf(ST[0][3], ST[1][0]), ST[1][1]);
        float t2 = fmaxf(fmaxf(ST[1][2], ST[1][3]), ST[2][0]);
        float t3 = fmaxf(fmaxf(ST[2][1], ST[2][2]), ST[2][3]);
        float t4 = fmaxf(fmaxf(ST[3][0], ST[3][1]), ST[3][2]);
        float u0 = fmaxf(fmaxf(t0, t1), t2);
        float u1 = fmaxf(fmaxf(t3, t4), ST[3][3]);
        mt = fmaxf(u0, u1);
      }
      mt = fmaxf(mt, __shfl_xor(mt, 16, 64));
      mt = fmaxf(mt, __shfl_xor(mt, 32, 64));
      // defer-max (T13): skip rescale when the whole wave's maxes are close
      if (!__all(mt <= m_ + 8.0f)) {
        const float mn = fmaxf(m_, mt);
        const float al = fexp2(m_ - mn);
        m_ = mn;
        lsum *= al;
#pragma unroll
        for (int di = 0; di < 4; ++di) OT[di] *= al;
      }
      // exp (raw v_exp_f32); row-sum is done on the MFMA pipe below
#pragma unroll
      for (int ni = 0; ni < 4; ++ni) {
        ST[ni][0] = fexp2(ST[ni][0] - m_);
        ST[ni][1] = fexp2(ST[ni][1] - m_);
        ST[ni][2] = fexp2(ST[ni][2] - m_);
        ST[ni][3] = fexp2(ST[ni][3] - m_);
      }

      // O^T += V^T P^T ; lsum += 1^T P^T (ones-MFMA row-sum).
      // pb[s] is lane-local = [ST[s][0..3], ST[s+2][0..3]]
      const ushort_t* vb = Vs + buf * 4096;
#pragma unroll
      for (int s = 0; s < 2; ++s) {
        int d0, d1, d2, d3;
        asm("v_cvt_pk_bf16_f32 %0, %1, %2" : "=v"(d0) : "v"(ST[s][0]), "v"(ST[s][1]));
        asm("v_cvt_pk_bf16_f32 %0, %1, %2" : "=v"(d1) : "v"(ST[s][2]), "v"(ST[s][3]));
        asm("v_cvt_pk_bf16_f32 %0, %1, %2" : "=v"(d2) : "v"(ST[s + 2][0]), "v"(ST[s + 2][1]));
        asm("v_cvt_pk_bf16_f32 %0, %1, %2" : "=v"(d3) : "v"(ST[s + 2][2]), "v"(ST[s + 2][3]));
        union { int i[4]; short8 v; } u;
        u.i[0] = d0; u.i[1] = d1; u.i[2] = d2; u.i[3] = d3;
        const short8 pb = u.v;
        __builtin_amdgcn_s_setprio(1);
#pragma unroll
        for (int di = 0; di < 4; ++di) {
          const ushort_t* vrow = vb + (di * 16 + l16) * 64;
          short8 vf = *(const short8*)(vrow + ((((s << 2) + quad) ^ vswz) << 3));
          OT[di] = MFMA16(vf, pb, OT[di]);
        }
        lsum = MFMA16(ones8, pb, lsum);  // D[m][q] = sum_k P[k][q], all m equal
        __builtin_amdgcn_s_setprio(0);
      }
    }

    __syncthreads();  // staging of next tile complete + all readers done
    buf ^= 1;
  }

  // normalize (lsum[0] is the full row-sum; no shuffles needed), store
  const float inv = 1.f / lsum[0];
  const int qq = wq0 + l16;
#pragma unroll
  for (int di = 0; di < 4; ++di) {
    ushort4v o4;
    o4.x = f2bf(OT[di][0] * inv);
    o4.y = f2bf(OT[di][1] * inv);
    o4.z = f2bf(OT[di][2] * inv);
    o4.w = f2bf(OT[di][3] * inv);
    *(ushort4v*)(attn_out + ((size_t)(b * 2048 + qq)) * 1024 + h * 64 +
                 di * 16 + quad * 4) = o4;
  }
}

// ---------------------------------------------------------------- launch
extern "C" void kernel_launch(void* const* d_in, const int* in_sizes, int n_in,
                              void* d_out, int out_size, void* d_ws, size_t ws_size,
                              hipStream_t stream) {
  const float* x      = (const float*)d_in[0];
  const int*   cs     = (const int*)d_in[2];
  const float* w_qkv  = (const float*)d_in[3];
  const float* w_proj = (const float*)d_in[4];
  const float* b_proj = (const float*)d_in[5];

  float* out     = (float*)d_out;
  float* present = out + (size_t)2 * 2048 * 1024;

  char* ws = (char*)d_ws;
  ushort_t* xb      = (ushort_t*)(ws);
  ushort_t* wqb     = (ushort_t*)(ws + ((size_t)8  << 20));
  ushort_t* wpb     = (ushort_t*)(ws + ((size_t)14 << 20));
  ushort_t* q_ws    = (ushort_t*)(ws + ((size_t)16 << 20));
  ushort_t* k_ws    = (ushort_t*)(ws + ((size_t)24 << 20));
  ushort_t* vT_ws   = (ushort_t*)(ws + ((size_t)32 << 20));
  ushort_t* attn_ws = (ushort_t*)(ws + ((size_t)40 << 20));

  // 8M elements total, 4/thread -> 8192 blocks exactly.
  cvt_all_kernel<<<8192, 256, 0, stream>>>(x, w_qkv, w_proj, xb, wqb, wpb);

  // gemm0: 32x24 tiles of 128x128, XCD rect 8tm x 12tn (tn-inner) -> grid 768
  gemm_bt<0, 128><<<768, 256, 0, stream>>>(xb, wqb, 1024, 12,
                                           nullptr, present, q_ws, k_ws, vT_ws, nullptr);

  attn_kernel<<<1024, 256, 0, stream>>>(q_ws, k_ws, vT_ws, attn_ws, cs);

  // gemm1: 32x16 tiles of 128x64, XCD rect 8tm x 8tn (tn-inner) -> grid 512
  gemm_bt<1, 64><<<512, 256, 0, stream>>>(attn_ws, wpb, 1024, 8,
                                          out, nullptr, nullptr, nullptr, nullptr, b_proj);
}